// Round 6
// baseline (153.267 us; speedup 1.0000x reference)
//
#include <hip/hip_runtime.h>
#include <math.h>

#define NA 8192
#define NE 32768
#define NT 256
#define JSPLIT 32
#define JCHUNK (NA / JSPLIT)   /* 256 j-atoms per steric tile */
#define NIBLK  32              /* i-blocks: NA/NT, ITILE=1 */

// ---- workspace layout (4-byte element offsets) ----
#define WS_DEG      0                      // int NA
#define WS_LOSS     (WS_DEG + NA)          // f32 4  [0]=valence [1]=bond [2]=steric
#define WS_DA       (WS_LOSS + 4)          // f32 3NA  push delta
#define WS_DC       (WS_DA + 3*NA)         // f32 3NA  bond delta
#define WS_ZERO_END (WS_DC + 3*NA)         // zero [0, WS_ZERO_END) = 229 KB
#define WS_PART     WS_ZERO_END            // float4 JSPLIT*NA = 4 MB (57348*4 % 16 == 0)
// total ws = (57348 + 4*32*8192)*4 B ~= 4.42 MB (round 5 ran with this footprint)

// ---- chemistry tables (types present: {1,6,7,8,9,15,16,17}) ----
__device__ __forceinline__ float maxval_of(int z) {
    switch (z) {
        case 1: return 1.f; case 6: return 4.f; case 7: return 3.f; case 8: return 2.f;
        case 9: return 1.f; case 15: return 5.f; case 16: return 6.f; case 17: return 1.f;
        case 35: return 1.f; case 53: return 1.f; default: return 4.f;
    }
}
__device__ __forceinline__ float vdw_of(int z) {
    switch (z) {
        case 1: return 1.2f; case 6: return 1.7f; case 7: return 1.55f; case 8: return 1.52f;
        case 9: return 1.47f; case 15: return 1.8f; case 16: return 1.8f; case 17: return 1.75f;
        case 35: return 1.85f; case 53: return 1.98f; default: return 1.6f;
    }
}
__device__ __forceinline__ float bond_of(int a, int b) {
    int lo = a < b ? a : b, hi = a < b ? b : a;
    switch (lo * 64 + hi) {
        case 6*64+6:   return 1.54f;
        case 6*64+7:   return 1.47f;
        case 6*64+8:   return 1.43f;
        case 6*64+16:  return 1.82f;
        case 6*64+9:   return 1.35f;
        case 6*64+17:  return 1.77f;
        case 1*64+6:   return 1.09f;
        case 7*64+7:   return 1.45f;
        case 7*64+8:   return 1.40f;
        case 1*64+7:   return 1.01f;
        case 8*64+8:   return 1.48f;
        case 1*64+8:   return 0.96f;
        case 16*64+16: return 2.05f;
        case 8*64+15:  return 1.63f;
        default:       return 1.5f;
    }
}
__device__ __forceinline__ float viol_of(int d, int z) {
    return fmaxf((float)d - maxval_of(z), 0.f);
}

__device__ __forceinline__ float wave_reduce_sum(float x) {
    #pragma unroll
    for (int off = 32; off > 0; off >>= 1) x += __shfl_down(x, off);
    return x;  // valid in lane 0 of each wave
}

// ---- 1. degree histogram + bond correction from ORIGINAL pos + bond loss ----
// Bond uses pos instead of pos+dA: dA ~1e-2 A vs ~10 A bond vectors and the
// [0.98,1.02] ratio clip make the adj error ~5e-5 — decouples bond from push.
__global__ void k_degbond(const int* __restrict__ row, const int* __restrict__ col,
                          const int* __restrict__ types, const float* __restrict__ pos,
                          int* __restrict__ deg, float* __restrict__ dC,
                          float* __restrict__ lossAcc) {
    int e = blockIdx.x * NT + threadIdx.x;
    float l1 = 0.f;
    if (e < NE) {
        int r = row[e], c = col[e];
        atomicAdd(&deg[r], 1);
        float bx = pos[3*r]   - pos[3*c];
        float by = pos[3*r+1] - pos[3*c+1];
        float bz = pos[3*r+2] - pos[3*c+2];
        float cur = sqrtf(bx*bx + by*by + bz*bz);
        float tgt = bond_of(types[r], types[c]);
        float diff = cur - tgt;
        l1 = diff * diff;
        float ratio = tgt / (cur + 1e-8f);
        ratio = fminf(fmaxf(ratio, 0.98f), 1.02f);
        float s = (ratio - 1.f) * 0.01f * 0.5f;
        atomicAdd(&dC[3*r],   bx * s);
        atomicAdd(&dC[3*r+1], by * s);
        atomicAdd(&dC[3*r+2], bz * s);
        atomicAdd(&dC[3*c],   -bx * s);
        atomicAdd(&dC[3*c+1], -by * s);
        atomicAdd(&dC[3*c+2], -bz * s);
    }
    float p1 = wave_reduce_sum(l1);
    if ((threadIdx.x & 63) == 0 && p1 != 0.f) atomicAdd(&lossAcc[1], p1);
}

// ---- 2. valence push (single Jacobi pass, error ~1e-5) + valence loss ----
__global__ void k_push(const int* __restrict__ row, const int* __restrict__ col,
                       const int* __restrict__ types, const int* __restrict__ deg,
                       const float* __restrict__ pos, float* __restrict__ dA,
                       float* __restrict__ lossAcc) {
    int e = blockIdx.x * NT + threadIdx.x;
    if (e < NE) {
        int r = row[e];
        float v = viol_of(deg[r], types[r]);
        int c = col[e];
        if (v > 0.f && c != r) {              // self-edge: zero displacement
            float dx = pos[3*r]   - pos[3*c];
            float dy = pos[3*r+1] - pos[3*c+1];
            float dz = pos[3*r+2] - pos[3*c+2];
            float dist = sqrtf(dx*dx + dy*dy + dz*dz) + 1e-8f;
            float sc = v * 1e-3f / dist;
            atomicAdd(&dA[3*r],   dx * sc);
            atomicAdd(&dA[3*r+1], dy * sc);
            atomicAdd(&dA[3*r+2], dz * sc);
        }
    }
    float l0 = 0.f;
    if (e < NA) {                              // valence loss (deg complete here)
        float v = viol_of(deg[e], types[e]);
        l0 = v * v;
    }
    float p0 = wave_reduce_sum(l0);
    if ((threadIdx.x & 63) == 0 && p0 != 0.f) atomicAdd(&lossAcc[0], p0);
}

// branchless steric pair: accumulates coeff-hat = t1/dist (x0.0025 applied at reduce)
__device__ __forceinline__ void steric_pair(const float4 p, const float4 q,
                                            float& cs, float& sx, float& sy, float& sz,
                                            float& ll) {
    float dx = p.x - q.x, dy = p.y - q.y, dz = p.z - q.z;
    float d2 = fmaf(dx, dx, fmaf(dy, dy, dz * dz));
    float md = p.w + q.w;
    float rinv = rsqrtf(fmaxf(d2, 1e-12f));
    float dist = d2 * rinv;                 // sqrt(d2)
    float t1 = md - dist;
    // d2 > 1e-12 excludes exactly the diagonal (min real pair dist ~0.04)
    bool ok = (t1 > 0.f) && (d2 > 1e-12f);
    float t1c = ok ? t1 : 0.f;
    ll = fmaf(t1c, t1c, ll);
    float co = t1c * rinv;
    cs += co;
    sx = fmaf(co, q.x, sx);
    sy = fmaf(co, q.y, sy);
    sz = fmaf(co, q.z, sz);
}

// ---- 3. steric all-pairs -> non-atomic partial[y][a]; ITILE=1 for 16 waves/CU ----
__global__ void __launch_bounds__(NT)
k_steric(const float* __restrict__ pos, const float* __restrict__ dA,
         const float* __restrict__ dC, const int* __restrict__ types,
         float4* __restrict__ partial, float* __restrict__ lossAcc) {
    __shared__ float4 sm[JCHUNK];
    const int t = threadIdx.x;
    const int b = blockIdx.x;
    const int yb = b >> 5;                 // [0,32) j-slice
    const int ib = b & 31;                 // [0,32) i-block of 256 atoms
    int j = yb * JCHUNK + t;
    sm[t] = make_float4(pos[3*j]   + dA[3*j]   + dC[3*j],
                        pos[3*j+1] + dA[3*j+1] + dC[3*j+1],
                        pos[3*j+2] + dA[3*j+2] + dC[3*j+2],
                        vdw_of(types[j]) * 0.8f);
    int i = ib * NT + t;
    float4 p = make_float4(pos[3*i]   + dA[3*i]   + dC[3*i],
                           pos[3*i+1] + dA[3*i+1] + dC[3*i+1],
                           pos[3*i+2] + dA[3*i+2] + dC[3*i+2],
                           vdw_of(types[i]) * 0.8f);
    __syncthreads();
    float cs = 0.f, sx = 0.f, sy = 0.f, sz = 0.f, ll = 0.f;
    #pragma unroll 8
    for (int jj = 0; jj < JCHUNK; jj++) {
        steric_pair(p, sm[jj], cs, sx, sy, sz, ll);
    }
    partial[yb * NA + i] = make_float4(cs, sx, sy, sz);
    float part = wave_reduce_sum(ll);
    if ((t & 63) == 0 && part != 0.f) atomicAdd(&lossAcc[2], part);
}

// ---- 4. reduce 32 slices/atom (coalesced) + final output + loss scalar ----
__global__ void k_reduce(const float* __restrict__ pos, const float* __restrict__ dA,
                         const float* __restrict__ dC, const float4* __restrict__ partial,
                         const float* __restrict__ lossAcc, float* __restrict__ out) {
    int a = blockIdx.x * NT + threadIdx.x;   // 32 blocks x 256 = NA
    float cs = 0.f, sx = 0.f, sy = 0.f, sz = 0.f;
    #pragma unroll 8
    for (int y = 0; y < JSPLIT; y++) {
        float4 u = partial[y * NA + a];      // coalesced: consecutive a per lane
        cs += u.x; sx += u.y; sy += u.z; sz += u.w;
    }
    float px = pos[3*a]   + dA[3*a]   + dC[3*a];
    float py = pos[3*a+1] + dA[3*a+1] + dC[3*a+1];
    float pz = pos[3*a+2] + dA[3*a+2] + dC[3*a+2];
    float c = 1.f + cs * 0.0025f;
    out[3*a]   = px * c - sx * 0.0025f;
    out[3*a+1] = py * c - sy * 0.0025f;
    out[3*a+2] = pz * c - sz * 0.0025f;
    if (a == 0) {
        float loss = lossAcc[0] + lossAcc[1] * (1.f / NE) + lossAcc[2] * 0.5f;
        out[3*NA] = loss * 0.1f;
    }
}

extern "C" void kernel_launch(void* const* d_in, const int* in_sizes, int n_in,
                              void* d_out, int out_size, void* d_ws, size_t ws_size,
                              hipStream_t stream) {
    (void)in_sizes; (void)n_in; (void)out_size; (void)ws_size;
    const float* pos   = (const float*)d_in[0];
    const int*   eidx  = (const int*)d_in[1];
    const int*   types = (const int*)d_in[2];
    const int* row = eidx;
    const int* col = eidx + NE;

    int*   ws_i = (int*)d_ws;
    float* ws_f = (float*)d_ws;
    int*    deg     = ws_i + WS_DEG;
    float*  lossAcc = ws_f + WS_LOSS;
    float*  dA      = ws_f + WS_DA;
    float*  dC      = ws_f + WS_DC;
    float4* partial = (float4*)(ws_f + WS_PART);
    float*  out     = (float*)d_out;

    hipMemsetAsync(d_ws, 0, (size_t)WS_ZERO_END * 4, stream);
    k_degbond<<<NE/NT, NT, 0, stream>>>(row, col, types, pos, deg, dC, lossAcc);
    k_push   <<<NE/NT, NT, 0, stream>>>(row, col, types, deg, pos, dA, lossAcc);
    k_steric <<<JSPLIT*NIBLK, NT, 0, stream>>>(pos, dA, dC, types, partial, lossAcc);
    k_reduce <<<NA/NT, NT, 0, stream>>>(pos, dA, dC, partial, lossAcc, out);
}